// Round 1
// baseline (2265.122 us; speedup 1.0000x reference)
//
#include <hip/hip_runtime.h>
#include <hip/hip_bf16.h>
#include <math.h>

#define N_PIX 3136
#define CDIM 432
#define NHEADS 8
#define HD 54
#define KW 7
#define KK 49
#define C2 392

// ---------------------------------------------------------------------------
// Generic tiled SGEMM: out = A @ B^T + bias.  A: (M x Kd) row-major,
// B: (Ncols x Kd) row-major.  M % 64 == 0, Kd % 16 == 0 (guaranteed here).
// mode 0: qkv split epilogue (O0=q scaled, O1=k, O2=v), mode 1: plain -> O0.
// ---------------------------------------------------------------------------
__global__ __launch_bounds__(256) void gemm_abt(
    const float* __restrict__ A, const float* __restrict__ B,
    const float* __restrict__ bias,
    float* __restrict__ O0, float* __restrict__ O1, float* __restrict__ O2,
    int M, int Ncols, int Kd, int mode, float qscale)
{
    __shared__ float As[16][65];
    __shared__ float Bs[16][65];
    const int tid = threadIdx.x;
    const int row0 = blockIdx.y * 64;
    const int col0 = blockIdx.x * 64;
    const int tx = tid & 15, ty = tid >> 4;
    const int lm = tid >> 2;          // 0..63
    const int lk = (tid & 3) << 2;    // 0,4,8,12
    float acc[4][4] = {};
    for (int k0 = 0; k0 < Kd; k0 += 16) {
        float4 av = *(const float4*)(A + (size_t)(row0 + lm) * Kd + k0 + lk);
        As[lk+0][lm] = av.x; As[lk+1][lm] = av.y;
        As[lk+2][lm] = av.z; As[lk+3][lm] = av.w;
        float4 bv = make_float4(0.f, 0.f, 0.f, 0.f);
        if (col0 + lm < Ncols)
            bv = *(const float4*)(B + (size_t)(col0 + lm) * Kd + k0 + lk);
        Bs[lk+0][lm] = bv.x; Bs[lk+1][lm] = bv.y;
        Bs[lk+2][lm] = bv.z; Bs[lk+3][lm] = bv.w;
        __syncthreads();
        #pragma unroll
        for (int kk = 0; kk < 16; kk++) {
            float a[4], b[4];
            #pragma unroll
            for (int i2 = 0; i2 < 4; i2++) a[i2] = As[kk][ty*4+i2];
            #pragma unroll
            for (int j2 = 0; j2 < 4; j2++) b[j2] = Bs[kk][tx*4+j2];
            #pragma unroll
            for (int i2 = 0; i2 < 4; i2++)
                #pragma unroll
                for (int j2 = 0; j2 < 4; j2++)
                    acc[i2][j2] += a[i2] * b[j2];
        }
        __syncthreads();
    }
    #pragma unroll
    for (int i2 = 0; i2 < 4; i2++) {
        int r = row0 + ty*4 + i2;
        #pragma unroll
        for (int j2 = 0; j2 < 4; j2++) {
            int cc = col0 + tx*4 + j2;
            if (cc >= Ncols) continue;
            float val = acc[i2][j2] + bias[cc];
            if (mode == 0) {
                int s = cc / CDIM, c = cc % CDIM;
                float* p = (s == 0) ? O0 : (s == 1 ? O1 : O2);
                if (s == 0) val *= qscale;
                p[(size_t)r * CDIM + c] = val;
            } else {
                O0[(size_t)r * Ncols + cc] = val;
            }
        }
    }
}

// ---------------------------------------------------------------------------
// Neighborhood attention: one wave per (pixel, head). lane t in [0,49):
// logits + rpb, softmax across 49 lanes via shfl.
// ---------------------------------------------------------------------------
__global__ __launch_bounds__(256) void attn_kernel(
    const float* __restrict__ q, const float* __restrict__ k,
    const float* __restrict__ rpb, float* __restrict__ attn)
{
    int wave = blockIdx.x * 4 + (threadIdx.x >> 6);
    int lane = threadIdx.x & 63;
    int n = wave >> 3, h = wave & 7;
    if (n >= N_PIX) return;
    int i = n / 56, j = n % 56;
    int ni = min(max(i - 3, 0), 49), nj = min(max(j - 3, 0), 49);
    int t = lane, u = t / 7, v = t % 7;
    float logit = -1e30f;
    if (t < KK) {
        int nb = (ni + u) * 56 + (nj + v);
        const float* qp = q + (size_t)n * CDIM + h * HD;
        const float* kp = k + (size_t)nb * CDIM + h * HD;
        float s = 0.f;
        #pragma unroll
        for (int d = 0; d < HD; d++) s += qp[d] * kp[d];
        int ri = 6 - (i - ni) + u;
        int rj = 6 - (j - nj) + v;
        logit = s + rpb[h * 169 + ri * 13 + rj];
    }
    float m = logit;
    #pragma unroll
    for (int off = 32; off; off >>= 1) m = fmaxf(m, __shfl_xor(m, off));
    float e = (t < KK) ? expf(logit - m) : 0.f;
    float ssum = e;
    #pragma unroll
    for (int off = 32; off; off >>= 1) ssum += __shfl_xor(ssum, off);
    if (t < KK) attn[(size_t)n * C2 + h * KK + t] = e / ssum;
}

// had = q_scaled * k * scale  (q already has one factor of scale)
__global__ __launch_bounds__(256) void had_kernel(
    const float* __restrict__ q, const float* __restrict__ k,
    float* __restrict__ had, float scale)
{
    int id = blockIdx.x * 256 + threadIdx.x;
    if (id >= N_PIX * CDIM) return;
    had[id] = q[id] * k[id] * scale;
}

// grouped 7x7 conv (54 groups of 8 in/out channels) + bias + exact GELU
__global__ __launch_bounds__(256) void conv1_gelu(
    const float* __restrict__ had, const float* __restrict__ w,
    const float* __restrict__ b, float* __restrict__ out)
{
    int id = blockIdx.x * 256 + threadIdx.x;
    if (id >= N_PIX * CDIM) return;
    int n = id / CDIM, o = id % CDIM;
    int i = n / 56, j = n % 56;
    int base = (o >> 3) << 3;
    float acc = b[o];
    const float* wp = w + (size_t)o * 8 * KK;
    for (int u = 0; u < 7; u++) {
        int pi = i + u - 3;
        if (pi < 0 || pi >= 56) continue;
        for (int v = 0; v < 7; v++) {
            int pj = j + v - 3;
            if (pj < 0 || pj >= 56) continue;
            const float* hp = had + (size_t)(pi * 56 + pj) * CDIM + base;
            int wo = u * 7 + v;
            #pragma unroll
            for (int icl = 0; icl < 8; icl++)
                acc += hp[icl] * wp[icl * KK + wo];
        }
    }
    out[id] = 0.5f * acc * (1.0f + erff(acc * 0.70710678118654752f));
}

// softmax over 392 channels, in place, one block (128 thr) per pixel
__global__ __launch_bounds__(128) void softmax392(float* __restrict__ h2)
{
    __shared__ float red[128];
    int n = blockIdx.x, tid = threadIdx.x;
    float* row = h2 + (size_t)n * C2;
    float m = -1e30f;
    for (int c = tid; c < C2; c += 128) m = fmaxf(m, row[c]);
    red[tid] = m; __syncthreads();
    for (int s = 64; s; s >>= 1) {
        if (tid < s) red[tid] = fmaxf(red[tid], red[tid + s]);
        __syncthreads();
    }
    m = red[0]; __syncthreads();
    float loc = 0.f;
    for (int c = tid; c < C2; c += 128) {
        float e = expf(row[c] - m);
        row[c] = e; loc += e;
    }
    red[tid] = loc; __syncthreads();
    for (int s = 64; s; s >>= 1) {
        if (tid < s) red[tid] += red[tid + s];
        __syncthreads();
    }
    float inv = 1.0f / red[0];
    for (int c = tid; c < C2; c += 128) row[c] *= inv;
}

__global__ __launch_bounds__(256) void ghost_transpose(
    const float* __restrict__ g, float* __restrict__ gt)
{
    int id = blockIdx.x * 256 + threadIdx.x;
    if (id >= CDIM * KK) return;
    int c = id / KK, t = id % KK;
    gt[t * CDIM + c] = g[id];
}

// combine: one wave per (pixel, head); lane d in [0,54):
//   av[d]   = sum_t (attn[t]+hat[t]) * v_clipped[t, c]
//   elsa[d] = sum_t v_padded[t, c] * ((d<27?attn[t]:hat[t]) + ghostT[t,c])
__global__ __launch_bounds__(256) void combine_kernel(
    const float* __restrict__ v, const float* __restrict__ attn,
    const float* __restrict__ hat, const float* __restrict__ ghostT,
    float* __restrict__ comb)
{
    int wave = blockIdx.x * 4 + (threadIdx.x >> 6);
    int lane = threadIdx.x & 63;
    int n = wave >> 3, h = wave & 7;
    if (n >= N_PIX || lane >= HD) return;
    int i = n / 56, j = n % 56;
    int ni = min(max(i - 3, 0), 49), nj = min(max(j - 3, 0), 49);
    int d = lane, c = h * HD + d;
    float av = 0.f, elsa = 0.f;
    const float* an = attn + (size_t)n * C2 + h * KK;
    const float* hn = hat + (size_t)n * C2 + h * KK;
    for (int t = 0; t < KK; t++) {
        int u = t / 7, vv = t % 7;
        float at = an[t], ht = hn[t];
        int nb = (ni + u) * 56 + (nj + vv);
        av += (at + ht) * v[(size_t)nb * CDIM + c];
        int pi = i + u - 3, pj = j + vv - 3;
        float vp = 0.f;
        if (pi >= 0 && pi < 56 && pj >= 0 && pj < 56)
            vp = v[(size_t)(pi * 56 + pj) * CDIM + c];
        float asel = (d < 27) ? at : ht;
        elsa += vp * (asel + ghostT[t * CDIM + c]);
    }
    comb[(size_t)n * 864 + h * 108 + d] = av;
    comb[(size_t)n * 864 + h * 108 + 54 + d] = elsa;
}

extern "C" void kernel_launch(void* const* d_in, const int* in_sizes, int n_in,
                              void* d_out, int out_size, void* d_ws, size_t ws_size,
                              hipStream_t stream)
{
    const float* x       = (const float*)d_in[0];
    const float* qkv_w   = (const float*)d_in[1];
    const float* qkv_b   = (const float*)d_in[2];
    const float* rpb     = (const float*)d_in[3];
    const float* conv1_w = (const float*)d_in[4];
    const float* conv1_b = (const float*)d_in[5];
    const float* conv2_w = (const float*)d_in[6];
    const float* conv2_b = (const float*)d_in[7];
    const float* ghost   = (const float*)d_in[8];
    const float* proj2_w = (const float*)d_in[9];
    const float* proj2_b = (const float*)d_in[10];
    float* out = (float*)d_out;

    float* ws = (float*)d_ws;
    const size_t NC = (size_t)N_PIX * CDIM;       // 1354752
    const size_t NA = (size_t)N_PIX * C2;         // 1229312
    float* q      = ws;
    float* k      = q + NC;
    float* v      = k + NC;
    float* attn   = v + NC;
    float* hat    = attn + NA;                    // also conv2 output buffer
    float* had    = hat + NA;
    float* hbuf   = had + NC;
    float* comb   = hbuf + NC;                    // N_PIX * 864
    float* ghostT = comb + (size_t)N_PIX * 864;   // 21168

    const float scale = 0.13608276348795434f;     // 54^-0.5

    ghost_transpose<<<(CDIM * KK + 255) / 256, 256, 0, stream>>>(ghost, ghostT);

    // qkv = x @ qkv_w^T + b  -> split q(*scale), k, v
    gemm_abt<<<dim3((1296 + 63) / 64, N_PIX / 64), 256, 0, stream>>>(
        x, qkv_w, qkv_b, q, k, v, N_PIX, 1296, CDIM, 0, scale);

    attn_kernel<<<(N_PIX * NHEADS) / 4, 256, 0, stream>>>(q, k, rpb, attn);

    had_kernel<<<(int)(NC / 256), 256, 0, stream>>>(q, k, had, scale);

    conv1_gelu<<<(int)(NC / 256), 256, 0, stream>>>(had, conv1_w, conv1_b, hbuf);

    // conv2 (1x1) as GEMM -> hat buffer, then in-place softmax over 392
    gemm_abt<<<dim3((C2 + 63) / 64, N_PIX / 64), 256, 0, stream>>>(
        hbuf, conv2_w, conv2_b, hat, nullptr, nullptr, N_PIX, C2, CDIM, 1, 1.f);

    softmax392<<<N_PIX, 128, 0, stream>>>(hat);

    combine_kernel<<<(N_PIX * NHEADS) / 4, 256, 0, stream>>>(v, attn, hat, ghostT, comb);

    // out = comb @ proj2_w^T + b
    gemm_abt<<<dim3((CDIM + 63) / 64, N_PIX / 64), 256, 0, stream>>>(
        comb, proj2_w, proj2_b, out, nullptr, nullptr, N_PIX, CDIM, 864, 1, 1.f);
}

// Round 2
// 389.747 us; speedup vs baseline: 5.8118x; 5.8118x over previous
//
#include <hip/hip_runtime.h>
#include <hip/hip_bf16.h>
#include <math.h>

#define N_PIX 3136
#define CDIM 432
#define NHEADS 8
#define HD 54
#define KW 7
#define KK 49
#define C2 392

// ---------------------------------------------------------------------------
// Generic tiled SGEMM: out = A @ B^T + bias.  A: (M x Kd) row-major,
// B: (Ncols x Kd) row-major.  M % 64 == 0, Kd % 16 == 0 (guaranteed here).
// mode 0: qkv split epilogue (O0=q scaled, O1=k, O2=v), mode 1: plain -> O0.
// ---------------------------------------------------------------------------
__global__ __launch_bounds__(256) void gemm_abt(
    const float* __restrict__ A, const float* __restrict__ B,
    const float* __restrict__ bias,
    float* __restrict__ O0, float* __restrict__ O1, float* __restrict__ O2,
    int M, int Ncols, int Kd, int mode, float qscale)
{
    __shared__ float As[16][65];
    __shared__ float Bs[16][65];
    const int tid = threadIdx.x;
    const int row0 = blockIdx.y * 64;
    const int col0 = blockIdx.x * 64;
    const int tx = tid & 15, ty = tid >> 4;
    const int lm = tid >> 2;          // 0..63
    const int lk = (tid & 3) << 2;    // 0,4,8,12
    float acc[4][4] = {};
    for (int k0 = 0; k0 < Kd; k0 += 16) {
        float4 av = *(const float4*)(A + (size_t)(row0 + lm) * Kd + k0 + lk);
        As[lk+0][lm] = av.x; As[lk+1][lm] = av.y;
        As[lk+2][lm] = av.z; As[lk+3][lm] = av.w;
        float4 bv = make_float4(0.f, 0.f, 0.f, 0.f);
        if (col0 + lm < Ncols)
            bv = *(const float4*)(B + (size_t)(col0 + lm) * Kd + k0 + lk);
        Bs[lk+0][lm] = bv.x; Bs[lk+1][lm] = bv.y;
        Bs[lk+2][lm] = bv.z; Bs[lk+3][lm] = bv.w;
        __syncthreads();
        #pragma unroll
        for (int kk = 0; kk < 16; kk++) {
            float a[4], b[4];
            #pragma unroll
            for (int i2 = 0; i2 < 4; i2++) a[i2] = As[kk][ty*4+i2];
            #pragma unroll
            for (int j2 = 0; j2 < 4; j2++) b[j2] = Bs[kk][tx*4+j2];
            #pragma unroll
            for (int i2 = 0; i2 < 4; i2++)
                #pragma unroll
                for (int j2 = 0; j2 < 4; j2++)
                    acc[i2][j2] += a[i2] * b[j2];
        }
        __syncthreads();
    }
    #pragma unroll
    for (int i2 = 0; i2 < 4; i2++) {
        int r = row0 + ty*4 + i2;
        #pragma unroll
        for (int j2 = 0; j2 < 4; j2++) {
            int cc = col0 + tx*4 + j2;
            if (cc >= Ncols) continue;
            float val = acc[i2][j2] + bias[cc];
            if (mode == 0) {
                int s = cc / CDIM, c = cc % CDIM;
                float* p = (s == 0) ? O0 : (s == 1 ? O1 : O2);
                if (s == 0) val *= qscale;
                p[(size_t)r * CDIM + c] = val;
            } else {
                O0[(size_t)r * Ncols + cc] = val;
            }
        }
    }
}

// ---------------------------------------------------------------------------
// Neighborhood attention: one wave per (pixel, head). lane t in [0,49):
// logits + rpb, softmax across 49 lanes via shfl.
// ---------------------------------------------------------------------------
__global__ __launch_bounds__(256) void attn_kernel(
    const float* __restrict__ q, const float* __restrict__ k,
    const float* __restrict__ rpb, float* __restrict__ attn)
{
    int wave = blockIdx.x * 4 + (threadIdx.x >> 6);
    int lane = threadIdx.x & 63;
    int n = wave >> 3, h = wave & 7;
    if (n >= N_PIX) return;
    int i = n / 56, j = n % 56;
    int ni = min(max(i - 3, 0), 49), nj = min(max(j - 3, 0), 49);
    int t = lane, u = t / 7, v = t % 7;
    float logit = -1e30f;
    if (t < KK) {
        int nb = (ni + u) * 56 + (nj + v);
        const float* qp = q + (size_t)n * CDIM + h * HD;
        const float* kp = k + (size_t)nb * CDIM + h * HD;
        float s = 0.f;
        #pragma unroll
        for (int d = 0; d < HD; d++) s += qp[d] * kp[d];
        int ri = 6 - (i - ni) + u;
        int rj = 6 - (j - nj) + v;
        logit = s + rpb[h * 169 + ri * 13 + rj];
    }
    float m = logit;
    #pragma unroll
    for (int off = 32; off; off >>= 1) m = fmaxf(m, __shfl_xor(m, off));
    float e = (t < KK) ? expf(logit - m) : 0.f;
    float ssum = e;
    #pragma unroll
    for (int off = 32; off; off >>= 1) ssum += __shfl_xor(ssum, off);
    if (t < KK) attn[(size_t)n * C2 + h * KK + t] = e / ssum;
}

// had = q_scaled * k * scale  (q already has one factor of scale)
__global__ __launch_bounds__(256) void had_kernel(
    const float* __restrict__ q, const float* __restrict__ k,
    float* __restrict__ had, float scale)
{
    int id = blockIdx.x * 256 + threadIdx.x;
    if (id >= N_PIX * CDIM) return;
    had[id] = q[id] * k[id] * scale;
}

// ---------------------------------------------------------------------------
// Grouped 7x7 conv (54 groups of 8 in/out ch) + bias + exact GELU. v2:
// block = (group g, row-tile of 4 rows), 256 thr = 4 waves (1 row each).
// lane = ic*8+oc. Weights in registers (49/lane); had tile in LDS
// [10 rows][8 ic][68 cols] (stride 68 floats -> b128 reads tile all 32
// banks conflict-free, 8-lane broadcast). 4 output cols per lane per pass,
// shfl-reduce over ic bits (8,16,32).
// ---------------------------------------------------------------------------
#define TH 4
__global__ __launch_bounds__(256) void conv1_gelu_v2(
    const float* __restrict__ had, const float* __restrict__ w,
    const float* __restrict__ b, float* __restrict__ out)
{
    int g = blockIdx.x % 54;
    int rt = blockIdx.x / 54;      // 0..13
    int r0 = rt * TH;
    int tid = threadIdx.x;
    int waveid = tid >> 6, lane = tid & 63;
    int ic = lane >> 3, oc = lane & 7;

    __shared__ float smem[10][8][68];

    float* sflat = &smem[0][0][0];
    for (int i = tid; i < 10 * 8 * 68; i += 256) sflat[i] = 0.f;

    // weights: conv1_w layout (432, 8, 7, 7)
    float wreg[49];
    {
        const float* wp = w + ((size_t)(g * 8 + oc) * 8 + ic) * 49;
        #pragma unroll
        for (int t = 0; t < 49; t++) wreg[t] = wp[t];
    }
    __syncthreads();

    // stage had rows r0-3 .. r0+6 (clamped), cols 0..55 -> cidx 3..58
    {
        int lic = tid & 7;
        int lpj = (tid >> 3) & 31;
        for (int rr = 0; rr < 10; rr++) {
            int pi = r0 - 3 + rr;
            if (pi < 0 || pi >= 56) continue;
            #pragma unroll
            for (int p0 = 0; p0 < 56; p0 += 32) {
                int pj = p0 + lpj;
                if (pj < 56)
                    smem[rr][lic][pj + 3] =
                        had[(size_t)(pi * 56 + pj) * CDIM + g * 8 + lic];
            }
        }
    }
    __syncthreads();

    int r = r0 + waveid;
    float bias_o = b[g * 8 + oc];
    for (int j0 = 0; j0 < 56; j0 += 4) {
        float acc0 = 0.f, acc1 = 0.f, acc2 = 0.f, acc3 = 0.f;
        #pragma unroll
        for (int u = 0; u < 7; u++) {
            const float* rp = &smem[waveid + u][ic][j0];
            float4 c0 = *(const float4*)(rp);
            float4 c1 = *(const float4*)(rp + 4);
            float4 c2 = *(const float4*)(rp + 8);
            float col[12] = {c0.x, c0.y, c0.z, c0.w,
                             c1.x, c1.y, c1.z, c1.w,
                             c2.x, c2.y, c2.z, c2.w};
            #pragma unroll
            for (int v = 0; v < 7; v++) {
                float wv = wreg[u * 7 + v];
                acc0 += wv * col[v + 0];
                acc1 += wv * col[v + 1];
                acc2 += wv * col[v + 2];
                acc3 += wv * col[v + 3];
            }
        }
        float accs[4] = {acc0, acc1, acc2, acc3};
        #pragma unroll
        for (int jj = 0; jj < 4; jj++) {
            float s = accs[jj];
            s += __shfl_xor(s, 8);
            s += __shfl_xor(s, 16);
            s += __shfl_xor(s, 32);
            accs[jj] = s;
        }
        if (ic == 0) {
            #pragma unroll
            for (int jj = 0; jj < 4; jj++) {
                float a = accs[jj] + bias_o;
                float gl = 0.5f * a * (1.0f + erff(a * 0.70710678118654752f));
                out[(size_t)(r * 56 + j0 + jj) * CDIM + g * 8 + oc] = gl;
            }
        }
    }
}

// softmax over 392 channels, in place, one block (128 thr) per pixel
__global__ __launch_bounds__(128) void softmax392(float* __restrict__ h2)
{
    __shared__ float red[128];
    int n = blockIdx.x, tid = threadIdx.x;
    float* row = h2 + (size_t)n * C2;
    float m = -1e30f;
    for (int c = tid; c < C2; c += 128) m = fmaxf(m, row[c]);
    red[tid] = m; __syncthreads();
    for (int s = 64; s; s >>= 1) {
        if (tid < s) red[tid] = fmaxf(red[tid], red[tid + s]);
        __syncthreads();
    }
    m = red[0]; __syncthreads();
    float loc = 0.f;
    for (int c = tid; c < C2; c += 128) {
        float e = expf(row[c] - m);
        row[c] = e; loc += e;
    }
    red[tid] = loc; __syncthreads();
    for (int s = 64; s; s >>= 1) {
        if (tid < s) red[tid] += red[tid + s];
        __syncthreads();
    }
    float inv = 1.0f / red[0];
    for (int c = tid; c < C2; c += 128) row[c] *= inv;
}

__global__ __launch_bounds__(256) void ghost_transpose(
    const float* __restrict__ g, float* __restrict__ gt)
{
    int id = blockIdx.x * 256 + threadIdx.x;
    if (id >= CDIM * KK) return;
    int c = id / KK, t = id % KK;
    gt[t * CDIM + c] = g[id];
}

// combine: one wave per (pixel, head); lane d in [0,54):
//   av[d]   = sum_t (attn[t]+hat[t]) * v_clipped[t, c]
//   elsa[d] = sum_t v_padded[t, c] * ((d<27?attn[t]:hat[t]) + ghostT[t,c])
__global__ __launch_bounds__(256) void combine_kernel(
    const float* __restrict__ v, const float* __restrict__ attn,
    const float* __restrict__ hat, const float* __restrict__ ghostT,
    float* __restrict__ comb)
{
    int wave = blockIdx.x * 4 + (threadIdx.x >> 6);
    int lane = threadIdx.x & 63;
    int n = wave >> 3, h = wave & 7;
    if (n >= N_PIX || lane >= HD) return;
    int i = n / 56, j = n % 56;
    int ni = min(max(i - 3, 0), 49), nj = min(max(j - 3, 0), 49);
    int d = lane, c = h * HD + d;
    float av = 0.f, elsa = 0.f;
    const float* an = attn + (size_t)n * C2 + h * KK;
    const float* hn = hat + (size_t)n * C2 + h * KK;
    for (int t = 0; t < KK; t++) {
        int u = t / 7, vv = t % 7;
        float at = an[t], ht = hn[t];
        int nb = (ni + u) * 56 + (nj + vv);
        av += (at + ht) * v[(size_t)nb * CDIM + c];
        int pi = i + u - 3, pj = j + vv - 3;
        float vp = 0.f;
        if (pi >= 0 && pi < 56 && pj >= 0 && pj < 56)
            vp = v[(size_t)(pi * 56 + pj) * CDIM + c];
        float asel = (d < 27) ? at : ht;
        elsa += vp * (asel + ghostT[t * CDIM + c]);
    }
    comb[(size_t)n * 864 + h * 108 + d] = av;
    comb[(size_t)n * 864 + h * 108 + 54 + d] = elsa;
}

extern "C" void kernel_launch(void* const* d_in, const int* in_sizes, int n_in,
                              void* d_out, int out_size, void* d_ws, size_t ws_size,
                              hipStream_t stream)
{
    const float* x       = (const float*)d_in[0];
    const float* qkv_w   = (const float*)d_in[1];
    const float* qkv_b   = (const float*)d_in[2];
    const float* rpb     = (const float*)d_in[3];
    const float* conv1_w = (const float*)d_in[4];
    const float* conv1_b = (const float*)d_in[5];
    const float* conv2_w = (const float*)d_in[6];
    const float* conv2_b = (const float*)d_in[7];
    const float* ghost   = (const float*)d_in[8];
    const float* proj2_w = (const float*)d_in[9];
    const float* proj2_b = (const float*)d_in[10];
    float* out = (float*)d_out;

    float* ws = (float*)d_ws;
    const size_t NC = (size_t)N_PIX * CDIM;       // 1354752
    const size_t NA = (size_t)N_PIX * C2;         // 1229312
    float* q      = ws;
    float* k      = q + NC;
    float* v      = k + NC;
    float* attn   = v + NC;
    float* hat    = attn + NA;                    // also conv2 output buffer
    float* had    = hat + NA;
    float* hbuf   = had + NC;
    float* comb   = hbuf + NC;                    // N_PIX * 864
    float* ghostT = comb + (size_t)N_PIX * 864;   // 21168

    const float scale = 0.13608276348795434f;     // 54^-0.5

    ghost_transpose<<<(CDIM * KK + 255) / 256, 256, 0, stream>>>(ghost, ghostT);

    // qkv = x @ qkv_w^T + b  -> split q(*scale), k, v
    gemm_abt<<<dim3((1296 + 63) / 64, N_PIX / 64), 256, 0, stream>>>(
        x, qkv_w, qkv_b, q, k, v, N_PIX, 1296, CDIM, 0, scale);

    attn_kernel<<<(N_PIX * NHEADS) / 4, 256, 0, stream>>>(q, k, rpb, attn);

    had_kernel<<<(int)(NC / 256), 256, 0, stream>>>(q, k, had, scale);

    conv1_gelu_v2<<<54 * 14, 256, 0, stream>>>(had, conv1_w, conv1_b, hbuf);

    // conv2 (1x1) as GEMM -> hat buffer, then in-place softmax over 392
    gemm_abt<<<dim3((C2 + 63) / 64, N_PIX / 64), 256, 0, stream>>>(
        hbuf, conv2_w, conv2_b, hat, nullptr, nullptr, N_PIX, C2, CDIM, 1, 1.f);

    softmax392<<<N_PIX, 128, 0, stream>>>(hat);

    combine_kernel<<<(N_PIX * NHEADS) / 4, 256, 0, stream>>>(v, attn, hat, ghostT, comb);

    // out = comb @ proj2_w^T + b
    gemm_abt<<<dim3((CDIM + 63) / 64, N_PIX / 64), 256, 0, stream>>>(
        comb, proj2_w, proj2_b, out, nullptr, nullptr, N_PIX, CDIM, 864, 1, 1.f);
}

// Round 3
// 214.285 us; speedup vs baseline: 10.5706x; 1.8188x over previous
//
#include <hip/hip_runtime.h>
#include <hip/hip_bf16.h>
#include <math.h>

#define N_PIX 3136
#define CDIM 432
#define NHEADS 8
#define HD 54
#define KK 49
#define C2 392

typedef __attribute__((ext_vector_type(8))) short bf16x8;
typedef __attribute__((ext_vector_type(4))) float f32x4;
typedef __attribute__((ext_vector_type(8))) unsigned short ushort8;

__device__ __forceinline__ void gload_lds16(const void* g, void* l) {
    __builtin_amdgcn_global_load_lds(
        (const __attribute__((address_space(1))) void*)g,
        (__attribute__((address_space(3))) void*)l, 16, 0, 0);
}

// storage permutation: element (r,k) of a row-major (.,Kp) bf16 matrix lives at
// chunk position ((k>>3)&7) ^ (r&7) within its 64-element k-block. This makes
// linear global_load_lds produce an XOR-swizzled LDS tile (bank-conflict-free
// ds_read_b128 at read-side XOR), per the both-sides-or-neither rule.
__device__ __forceinline__ size_t perm_off(int r, int k, int Kp) {
    int p = ((k >> 3) & 7) ^ (r & 7);
    return (size_t)r * Kp + ((k >> 6) << 6) + (p << 3) + (k & 7);
}

// fp32 -> permuted bf16 (pads rows [Mlog,Mpad) and cols [Klog,Kp) with zeros)
__global__ __launch_bounds__(256) void convert_perm(
    const float* __restrict__ src, __hip_bfloat16* __restrict__ dst,
    int Mlog, int Mpad, int Klog, int Kp)
{
    int chunks = Kp >> 3;
    int id = blockIdx.x * 256 + threadIdx.x;
    if (id >= Mpad * chunks) return;
    int r = id / chunks, cb = id % chunks;
    int k0 = cb << 3;
    __hip_bfloat16 vv[8];
    #pragma unroll
    for (int e = 0; e < 8; e++) {
        int k = k0 + e;
        float f = (r < Mlog && k < Klog) ? src[(size_t)r * Klog + k] : 0.f;
        vv[e] = __float2bfloat16(f);
    }
    int p = (cb & 7) ^ (r & 7);
    __hip_bfloat16* d = dst + (size_t)r * Kp + ((cb >> 3) << 6) + (p << 3);
    *(ushort8*)d = *(const ushort8*)vv;
}

// ---------------------------------------------------------------------------
// bf16 MFMA GEMM: out = A @ B^T + bias. A: (M x Kp) perm-bf16, B: (Npad x Kp)
// perm-bf16 (rows >= Nlog are zero). Tile 64x64, BK=64, 4 waves of 32x32.
// mode 0: qkv split epilogue (fp32 q*scale,k,v), mode 1: plain fp32 -> O0.
// ---------------------------------------------------------------------------
__global__ __launch_bounds__(256) void gemm_mfma(
    const __hip_bfloat16* __restrict__ A, const __hip_bfloat16* __restrict__ B,
    const float* __restrict__ bias,
    float* __restrict__ O0, float* __restrict__ O1, float* __restrict__ O2,
    int Nlog, int Kp, int mode, float qscale, int ldO)
{
    __shared__ __hip_bfloat16 lA[64 * 64];
    __shared__ __hip_bfloat16 lB[64 * 64];
    const int tid = threadIdx.x;
    const int w = tid >> 6, lane = tid & 63;
    const int row0 = blockIdx.y * 64, col0 = blockIdx.x * 64;
    const int wr = (w >> 1) * 32, wc = (w & 1) * 32;
    const int srow = lane >> 3, schk = lane & 7;
    f32x4 acc[2][2] = {};

    for (int k0 = 0; k0 < Kp; k0 += 64) {
        #pragma unroll
        for (int t = 0; t < 2; t++) {
            int lid = w * 2 + t;
            const __hip_bfloat16* ga =
                A + (size_t)(row0 + lid * 8 + srow) * Kp + k0 + schk * 8;
            gload_lds16(ga, &lA[lid * 8 * 64]);
            const __hip_bfloat16* gb =
                B + (size_t)(col0 + lid * 8 + srow) * Kp + k0 + schk * 8;
            gload_lds16(gb, &lB[lid * 8 * 64]);
        }
        __syncthreads();
        #pragma unroll
        for (int ks = 0; ks < 2; ks++) {
            bf16x8 af[2], bfr[2];
            int c = ks * 4 + (lane >> 4);
            #pragma unroll
            for (int mi = 0; mi < 2; mi++) {
                int ra = wr + mi * 16 + (lane & 15);
                af[mi] = *(const bf16x8*)&lA[ra * 64 + ((c ^ (ra & 7)) << 3)];
                int rb = wc + mi * 16 + (lane & 15);
                bfr[mi] = *(const bf16x8*)&lB[rb * 64 + ((c ^ (rb & 7)) << 3)];
            }
            #pragma unroll
            for (int mi = 0; mi < 2; mi++)
                #pragma unroll
                for (int ni = 0; ni < 2; ni++)
                    acc[mi][ni] = __builtin_amdgcn_mfma_f32_16x16x32_bf16(
                        af[mi], bfr[ni], acc[mi][ni], 0, 0, 0);
        }
        __syncthreads();
    }

    #pragma unroll
    for (int mi = 0; mi < 2; mi++) {
        #pragma unroll
        for (int ni = 0; ni < 2; ni++) {
            #pragma unroll
            for (int rr = 0; rr < 4; rr++) {
                int r = row0 + wr + mi * 16 + (lane >> 4) * 4 + rr;
                int cc = col0 + wc + ni * 16 + (lane & 15);
                if (cc >= Nlog) continue;
                float val = acc[mi][ni][rr] + bias[cc];
                if (mode == 0) {
                    int s = cc / CDIM, cch = cc - s * CDIM;
                    float* p = (s == 0) ? O0 : (s == 1 ? O1 : O2);
                    if (s == 0) val *= qscale;
                    p[(size_t)r * CDIM + cch] = val;
                } else {
                    O0[(size_t)r * ldO + cc] = val;
                }
            }
        }
    }
}

// ---------------------------------------------------------------------------
// Neighborhood attention: one wave per (pixel, head). lane t in [0,49):
// logits + rpb, softmax across 49 lanes via shfl.
// ---------------------------------------------------------------------------
__global__ __launch_bounds__(256) void attn_kernel(
    const float* __restrict__ q, const float* __restrict__ k,
    const float* __restrict__ rpb, float* __restrict__ attn)
{
    int wave = blockIdx.x * 4 + (threadIdx.x >> 6);
    int lane = threadIdx.x & 63;
    int n = wave >> 3, h = wave & 7;
    if (n >= N_PIX) return;
    int i = n / 56, j = n % 56;
    int ni = min(max(i - 3, 0), 49), nj = min(max(j - 3, 0), 49);
    int t = lane, u = t / 7, v = t % 7;
    float logit = -1e30f;
    if (t < KK) {
        int nb = (ni + u) * 56 + (nj + v);
        const float* qp = q + (size_t)n * CDIM + h * HD;
        const float* kp = k + (size_t)nb * CDIM + h * HD;
        float s = 0.f;
        #pragma unroll
        for (int d = 0; d < HD; d++) s += qp[d] * kp[d];
        int ri = 6 - (i - ni) + u;
        int rj = 6 - (j - nj) + v;
        logit = s + rpb[h * 169 + ri * 13 + rj];
    }
    float m = logit;
    #pragma unroll
    for (int off = 32; off; off >>= 1) m = fmaxf(m, __shfl_xor(m, off));
    float e = (t < KK) ? expf(logit - m) : 0.f;
    float ssum = e;
    #pragma unroll
    for (int off = 32; off; off >>= 1) ssum += __shfl_xor(ssum, off);
    if (t < KK) attn[(size_t)n * C2 + h * KK + t] = e / ssum;
}

// had = q_scaled * k * scale  (q already has one factor of scale)
__global__ __launch_bounds__(256) void had_kernel(
    const float* __restrict__ q, const float* __restrict__ k,
    float* __restrict__ had, float scale)
{
    int id = blockIdx.x * 256 + threadIdx.x;
    if (id >= N_PIX * CDIM) return;
    had[id] = q[id] * k[id] * scale;
}

// ---------------------------------------------------------------------------
// Grouped 7x7 conv (54 groups of 8 in/out ch) + bias + exact GELU ->
// permuted bf16 output (feeds the conv2 MFMA GEMM).
// ---------------------------------------------------------------------------
#define TH 4
__global__ __launch_bounds__(256) void conv1_gelu_v2(
    const float* __restrict__ had, const float* __restrict__ w,
    const float* __restrict__ b, __hip_bfloat16* __restrict__ out)
{
    int g = blockIdx.x % 54;
    int rt = blockIdx.x / 54;      // 0..13
    int r0 = rt * TH;
    int tid = threadIdx.x;
    int waveid = tid >> 6, lane = tid & 63;
    int ic = lane >> 3, oc = lane & 7;

    __shared__ float smem[10][8][68];

    float* sflat = &smem[0][0][0];
    for (int i = tid; i < 10 * 8 * 68; i += 256) sflat[i] = 0.f;

    float wreg[49];
    {
        const float* wp = w + ((size_t)(g * 8 + oc) * 8 + ic) * 49;
        #pragma unroll
        for (int t = 0; t < 49; t++) wreg[t] = wp[t];
    }
    __syncthreads();

    {
        int lic = tid & 7;
        int lpj = (tid >> 3) & 31;
        for (int rr = 0; rr < 10; rr++) {
            int pi = r0 - 3 + rr;
            if (pi < 0 || pi >= 56) continue;
            #pragma unroll
            for (int p0 = 0; p0 < 56; p0 += 32) {
                int pj = p0 + lpj;
                if (pj < 56)
                    smem[rr][lic][pj + 3] =
                        had[(size_t)(pi * 56 + pj) * CDIM + g * 8 + lic];
            }
        }
    }
    __syncthreads();

    int r = r0 + waveid;
    float bias_o = b[g * 8 + oc];
    for (int j0 = 0; j0 < 56; j0 += 4) {
        float acc0 = 0.f, acc1 = 0.f, acc2 = 0.f, acc3 = 0.f;
        #pragma unroll
        for (int u = 0; u < 7; u++) {
            const float* rp = &smem[waveid + u][ic][j0];
            float4 c0 = *(const float4*)(rp);
            float4 c1 = *(const float4*)(rp + 4);
            float4 c2 = *(const float4*)(rp + 8);
            float col[12] = {c0.x, c0.y, c0.z, c0.w,
                             c1.x, c1.y, c1.z, c1.w,
                             c2.x, c2.y, c2.z, c2.w};
            #pragma unroll
            for (int v = 0; v < 7; v++) {
                float wv = wreg[u * 7 + v];
                acc0 += wv * col[v + 0];
                acc1 += wv * col[v + 1];
                acc2 += wv * col[v + 2];
                acc3 += wv * col[v + 3];
            }
        }
        float accs[4] = {acc0, acc1, acc2, acc3};
        #pragma unroll
        for (int jj = 0; jj < 4; jj++) {
            float s = accs[jj];
            s += __shfl_xor(s, 8);
            s += __shfl_xor(s, 16);
            s += __shfl_xor(s, 32);
            accs[jj] = s;
        }
        if (ic == 0) {
            #pragma unroll
            for (int jj = 0; jj < 4; jj++) {
                float a = accs[jj] + bias_o;
                float gl = 0.5f * a * (1.0f + erff(a * 0.70710678118654752f));
                int n = r * 56 + j0 + jj;
                int kch = g * 8 + oc;
                out[perm_off(n, kch, 448)] = __float2bfloat16(gl);
            }
        }
    }
}

// softmax over 392 channels, in place, one block (128 thr) per pixel
__global__ __launch_bounds__(128) void softmax392(float* __restrict__ h2)
{
    __shared__ float red[128];
    int n = blockIdx.x, tid = threadIdx.x;
    float* row = h2 + (size_t)n * C2;
    float m = -1e30f;
    for (int c = tid; c < C2; c += 128) m = fmaxf(m, row[c]);
    red[tid] = m; __syncthreads();
    for (int s = 64; s; s >>= 1) {
        if (tid < s) red[tid] = fmaxf(red[tid], red[tid + s]);
        __syncthreads();
    }
    m = red[0]; __syncthreads();
    float loc = 0.f;
    for (int c = tid; c < C2; c += 128) {
        float e = expf(row[c] - m);
        row[c] = e; loc += e;
    }
    red[tid] = loc; __syncthreads();
    for (int s = 64; s; s >>= 1) {
        if (tid < s) red[tid] += red[tid + s];
        __syncthreads();
    }
    float inv = 1.0f / red[0];
    for (int c = tid; c < C2; c += 128) row[c] *= inv;
}

__global__ __launch_bounds__(256) void ghost_transpose(
    const float* __restrict__ g, float* __restrict__ gt)
{
    int id = blockIdx.x * 256 + threadIdx.x;
    if (id >= CDIM * KK) return;
    int c = id / KK, t = id % KK;
    gt[t * CDIM + c] = g[id];
}

// combine: one wave per (pixel, head); lane d in [0,54): writes permuted bf16
// comb rows (feeds proj2 MFMA GEMM).
__global__ __launch_bounds__(256) void combine_kernel(
    const float* __restrict__ v, const float* __restrict__ attn,
    const float* __restrict__ hat, const float* __restrict__ ghostT,
    __hip_bfloat16* __restrict__ comb)
{
    int wave = blockIdx.x * 4 + (threadIdx.x >> 6);
    int lane = threadIdx.x & 63;
    int n = wave >> 3, h = wave & 7;
    if (n >= N_PIX || lane >= HD) return;
    int i = n / 56, j = n % 56;
    int ni = min(max(i - 3, 0), 49), nj = min(max(j - 3, 0), 49);
    int d = lane, c = h * HD + d;
    float av = 0.f, elsa = 0.f;
    const float* an = attn + (size_t)n * C2 + h * KK;
    const float* hn = hat + (size_t)n * C2 + h * KK;
    for (int t = 0; t < KK; t++) {
        int u = t / 7, vv = t % 7;
        float at = an[t], ht = hn[t];
        int nb = (ni + u) * 56 + (nj + vv);
        av += (at + ht) * v[(size_t)nb * CDIM + c];
        int pi = i + u - 3, pj = j + vv - 3;
        float vp = 0.f;
        if (pi >= 0 && pi < 56 && pj >= 0 && pj < 56)
            vp = v[(size_t)(pi * 56 + pj) * CDIM + c];
        float asel = (d < 27) ? at : ht;
        elsa += vp * (asel + ghostT[t * CDIM + c]);
    }
    comb[perm_off(n, h * 108 + d, 896)] = __float2bfloat16(av);
    comb[perm_off(n, h * 108 + 54 + d, 896)] = __float2bfloat16(elsa);
}

extern "C" void kernel_launch(void* const* d_in, const int* in_sizes, int n_in,
                              void* d_out, int out_size, void* d_ws, size_t ws_size,
                              hipStream_t stream)
{
    const float* x       = (const float*)d_in[0];
    const float* qkv_w   = (const float*)d_in[1];
    const float* qkv_b   = (const float*)d_in[2];
    const float* rpb     = (const float*)d_in[3];
    const float* conv1_w = (const float*)d_in[4];
    const float* conv1_b = (const float*)d_in[5];
    const float* conv2_w = (const float*)d_in[6];
    const float* conv2_b = (const float*)d_in[7];
    const float* ghost   = (const float*)d_in[8];
    const float* proj2_w = (const float*)d_in[9];
    const float* proj2_b = (const float*)d_in[10];
    float* out = (float*)d_out;

    float* ws = (float*)d_ws;
    const size_t NC = (size_t)N_PIX * CDIM;       // 1354752
    const size_t NA = (size_t)N_PIX * C2;         // 1229312
    float* q      = ws;
    float* k      = q + NC;
    float* v      = k + NC;
    float* attn   = v + NC;
    float* hat    = attn + NA;
    float* had    = hat + NA;
    float* ghostT = had + NC;                     // 21168
    // bf16 region (16B aligned: 7898800 floats * 4 = 31,595,200 bytes)
    __hip_bfloat16* bfbase = (__hip_bfloat16*)(ghostT + 21168);
    __hip_bfloat16* xb     = bfbase;                    // 3136 x 448
    __hip_bfloat16* qkvwb  = xb    + (size_t)3136 * 448;
    __hip_bfloat16* c2wb   = qkvwb + (size_t)1344 * 448;
    __hip_bfloat16* p2wb   = c2wb  + (size_t)448 * 448;
    __hip_bfloat16* hb     = p2wb  + (size_t)448 * 896; // 3136 x 448
    __hip_bfloat16* cb     = hb    + (size_t)3136 * 448;// 3136 x 896

    const float scale = 0.13608276348795434f;     // 54^-0.5

    ghost_transpose<<<(CDIM * KK + 255) / 256, 256, 0, stream>>>(ghost, ghostT);

    convert_perm<<<686, 256, 0, stream>>>(x, xb, 3136, 3136, 432, 448);
    convert_perm<<<294, 256, 0, stream>>>(qkv_w, qkvwb, 1296, 1344, 432, 448);
    convert_perm<<<98,  256, 0, stream>>>(conv2_w, c2wb, 392, 448, 432, 448);
    convert_perm<<<196, 256, 0, stream>>>(proj2_w, p2wb, 432, 448, 864, 896);

    // qkv = x @ qkv_w^T + b  -> split q(*scale), k, v (fp32)
    gemm_mfma<<<dim3(21, 49), 256, 0, stream>>>(
        xb, qkvwb, qkv_b, q, k, v, 1296, 448, 0, scale, 0);

    attn_kernel<<<(N_PIX * NHEADS) / 4, 256, 0, stream>>>(q, k, rpb, attn);

    had_kernel<<<(int)(NC / 256), 256, 0, stream>>>(q, k, had, scale);

    conv1_gelu_v2<<<54 * 14, 256, 0, stream>>>(had, conv1_w, conv1_b, hb);

    gemm_mfma<<<dim3(7, 49), 256, 0, stream>>>(
        hb, c2wb, conv2_b, hat, nullptr, nullptr, 392, 448, 1, 1.f, 392);

    softmax392<<<N_PIX, 128, 0, stream>>>(hat);

    combine_kernel<<<(N_PIX * NHEADS) / 4, 256, 0, stream>>>(v, attn, hat, ghostT, cb);

    gemm_mfma<<<dim3(7, 49), 256, 0, stream>>>(
        cb, p2wb, proj2_b, out, nullptr, nullptr, 432, 896, 1, 1.f, 432);
}

// Round 4
// 167.138 us; speedup vs baseline: 13.5524x; 1.2821x over previous
//
#include <hip/hip_runtime.h>
#include <hip/hip_bf16.h>
#include <math.h>

#define N_PIX 3136
#define CDIM 432
#define NHEADS 8
#define HD 54
#define KK 49
#define C2 392

typedef __attribute__((ext_vector_type(8))) short bf16x8;
typedef __attribute__((ext_vector_type(4))) float f32x4;
typedef __attribute__((ext_vector_type(8))) unsigned short ushort8;

__device__ __forceinline__ void gload_lds16(const void* g, void* l) {
    __builtin_amdgcn_global_load_lds(
        (const __attribute__((address_space(1))) void*)g,
        (__attribute__((address_space(3))) void*)l, 16, 0, 0);
}

// storage permutation: element (r,k) of a row-major (.,Kp) bf16 matrix lives at
// chunk position ((k>>3)&7) ^ (r&7) within its 64-element k-block -> linear
// global_load_lds lands an XOR-swizzled LDS tile (conflict-free ds_read_b128).
__device__ __forceinline__ size_t perm_off(int r, int k, int Kp) {
    int p = ((k >> 3) & 7) ^ (r & 7);
    return (size_t)r * Kp + ((k >> 6) << 6) + (p << 3) + (k & 7);
}

__device__ __forceinline__ void convert_body(
    const float* __restrict__ src, __hip_bfloat16* __restrict__ dst,
    int Mlog, int Mpad, int Klog, int Kp, int id)
{
    int chunks = Kp >> 3;
    if (id >= Mpad * chunks) return;
    int r = id / chunks, cb = id % chunks;
    int k0 = cb << 3;
    __hip_bfloat16 vv[8];
    #pragma unroll
    for (int e = 0; e < 8; e++) {
        int k = k0 + e;
        float f = (r < Mlog && k < Klog) ? src[(size_t)r * Klog + k] : 0.f;
        vv[e] = __float2bfloat16(f);
    }
    int p = (cb & 7) ^ (r & 7);
    __hip_bfloat16* d = dst + (size_t)r * Kp + ((cb >> 3) << 6) + (p << 3);
    *(ushort8*)d = *(const ushort8*)vv;
}

// merged preprocessing: ghost transpose + 4 bf16 permuted conversions
__global__ __launch_bounds__(256) void prep_kernel(
    const float* __restrict__ x, const float* __restrict__ qkv_w,
    const float* __restrict__ conv2_w, const float* __restrict__ proj2_w,
    const float* __restrict__ ghost,
    __hip_bfloat16* __restrict__ xb, __hip_bfloat16* __restrict__ qkvwb,
    __hip_bfloat16* __restrict__ c2wb, __hip_bfloat16* __restrict__ p2wb,
    float* __restrict__ ghostT)
{
    int b = blockIdx.x;
    if (b < 83) {
        int id = b * 256 + threadIdx.x;
        if (id < CDIM * KK) {
            int cc = id / KK, t = id % KK;
            ghostT[t * CDIM + cc] = ghost[id];
        }
    } else if (b < 769) {
        convert_body(x, xb, 3136, 3136, 432, 448, (b - 83) * 256 + threadIdx.x);
    } else if (b < 1063) {
        convert_body(qkv_w, qkvwb, 1296, 1344, 432, 448, (b - 769) * 256 + threadIdx.x);
    } else if (b < 1161) {
        convert_body(conv2_w, c2wb, 392, 448, 432, 448, (b - 1063) * 256 + threadIdx.x);
    } else {
        convert_body(proj2_w, p2wb, 432, 448, 864, 896, (b - 1161) * 256 + threadIdx.x);
    }
}

// ---------------------------------------------------------------------------
// bf16 MFMA GEMM: out = A @ B^T + bias (64x64 tile, BK=64, 4 waves of 32x32)
// ---------------------------------------------------------------------------
__global__ __launch_bounds__(256) void gemm_mfma(
    const __hip_bfloat16* __restrict__ A, const __hip_bfloat16* __restrict__ B,
    const float* __restrict__ bias,
    float* __restrict__ O0, float* __restrict__ O1, float* __restrict__ O2,
    int Nlog, int Kp, int mode, float qscale, int ldO)
{
    __shared__ __hip_bfloat16 lA[64 * 64];
    __shared__ __hip_bfloat16 lB[64 * 64];
    const int tid = threadIdx.x;
    const int w = tid >> 6, lane = tid & 63;
    const int row0 = blockIdx.y * 64, col0 = blockIdx.x * 64;
    const int wr = (w >> 1) * 32, wc = (w & 1) * 32;
    const int srow = lane >> 3, schk = lane & 7;
    f32x4 acc[2][2] = {};

    for (int k0 = 0; k0 < Kp; k0 += 64) {
        #pragma unroll
        for (int t = 0; t < 2; t++) {
            int lid = w * 2 + t;
            const __hip_bfloat16* ga =
                A + (size_t)(row0 + lid * 8 + srow) * Kp + k0 + schk * 8;
            gload_lds16(ga, &lA[lid * 8 * 64]);
            const __hip_bfloat16* gb =
                B + (size_t)(col0 + lid * 8 + srow) * Kp + k0 + schk * 8;
            gload_lds16(gb, &lB[lid * 8 * 64]);
        }
        __syncthreads();
        #pragma unroll
        for (int ks = 0; ks < 2; ks++) {
            bf16x8 af[2], bfr[2];
            int c = ks * 4 + (lane >> 4);
            #pragma unroll
            for (int mi = 0; mi < 2; mi++) {
                int ra = wr + mi * 16 + (lane & 15);
                af[mi] = *(const bf16x8*)&lA[ra * 64 + ((c ^ (ra & 7)) << 3)];
                int rb = wc + mi * 16 + (lane & 15);
                bfr[mi] = *(const bf16x8*)&lB[rb * 64 + ((c ^ (rb & 7)) << 3)];
            }
            #pragma unroll
            for (int mi = 0; mi < 2; mi++)
                #pragma unroll
                for (int ni = 0; ni < 2; ni++)
                    acc[mi][ni] = __builtin_amdgcn_mfma_f32_16x16x32_bf16(
                        af[mi], bfr[ni], acc[mi][ni], 0, 0, 0);
        }
        __syncthreads();
    }

    #pragma unroll
    for (int mi = 0; mi < 2; mi++) {
        #pragma unroll
        for (int ni = 0; ni < 2; ni++) {
            #pragma unroll
            for (int rr = 0; rr < 4; rr++) {
                int r = row0 + wr + mi * 16 + (lane >> 4) * 4 + rr;
                int cc = col0 + wc + ni * 16 + (lane & 15);
                if (cc >= Nlog) continue;
                float val = acc[mi][ni][rr] + bias[cc];
                if (mode == 0) {
                    int s = cc / CDIM, cch = cc - s * CDIM;
                    float* p = (s == 0) ? O0 : (s == 1 ? O1 : O2);
                    if (s == 0) val *= qscale;
                    p[(size_t)r * CDIM + cch] = val;
                } else {
                    O0[(size_t)r * ldO + cc] = val;
                }
            }
        }
    }
}

// ---------------------------------------------------------------------------
// Neighborhood attention: one wave per (pixel, head), lane t in [0,49)
// ---------------------------------------------------------------------------
__global__ __launch_bounds__(256) void attn_kernel(
    const float* __restrict__ q, const float* __restrict__ k,
    const float* __restrict__ rpb, float* __restrict__ attn)
{
    int wave = blockIdx.x * 4 + (threadIdx.x >> 6);
    wave = __builtin_amdgcn_readfirstlane(wave);
    int lane = threadIdx.x & 63;
    int n = wave >> 3, h = wave & 7;
    int i = n / 56, j = n % 56;
    int ni = min(max(i - 3, 0), 49), nj = min(max(j - 3, 0), 49);
    int t = lane, u = t / 7, v = t % 7;
    float logit = -1e30f;
    if (t < KK) {
        int nb = (ni + u) * 56 + (nj + v);
        const float* qp = q + (size_t)n * CDIM + h * HD;
        const float* kp = k + (size_t)nb * CDIM + h * HD;
        float s = 0.f;
        #pragma unroll
        for (int d = 0; d < HD; d++) s += qp[d] * kp[d];
        int ri = 6 - (i - ni) + u;
        int rj = 6 - (j - nj) + v;
        logit = s + rpb[h * 169 + ri * 13 + rj];
    }
    float m = logit;
    #pragma unroll
    for (int off = 32; off; off >>= 1) m = fmaxf(m, __shfl_xor(m, off));
    float e = (t < KK) ? expf(logit - m) : 0.f;
    float ssum = e;
    #pragma unroll
    for (int off = 32; off; off >>= 1) ssum += __shfl_xor(ssum, off);
    if (t < KK) attn[(size_t)n * C2 + h * KK + t] = e / ssum;
}

// ---------------------------------------------------------------------------
// Grouped 7x7 conv + GELU, with had = q*k*scale fused into the staging loads.
// Output: permuted bf16 (feeds conv2 MFMA GEMM).
// ---------------------------------------------------------------------------
#define TH 4
__global__ __launch_bounds__(256) void conv1_gelu_v2(
    const float* __restrict__ q, const float* __restrict__ k,
    const float* __restrict__ w, const float* __restrict__ b,
    __hip_bfloat16* __restrict__ out, float scale)
{
    int g = blockIdx.x % 54;
    int rt = blockIdx.x / 54;      // 0..13
    int r0 = rt * TH;
    int tid = threadIdx.x;
    int waveid = tid >> 6, lane = tid & 63;
    int ic = lane >> 3, oc = lane & 7;

    __shared__ float smem[10][8][68];

    float* sflat = &smem[0][0][0];
    for (int i = tid; i < 10 * 8 * 68; i += 256) sflat[i] = 0.f;

    float wreg[49];
    {
        const float* wp = w + ((size_t)(g * 8 + oc) * 8 + ic) * 49;
        #pragma unroll
        for (int t = 0; t < 49; t++) wreg[t] = wp[t];
    }
    __syncthreads();

    {
        int lic = tid & 7;
        int lpj = (tid >> 3) & 31;
        for (int rr = 0; rr < 10; rr++) {
            int pi = r0 - 3 + rr;
            if (pi < 0 || pi >= 56) continue;
            #pragma unroll
            for (int p0 = 0; p0 < 56; p0 += 32) {
                int pj = p0 + lpj;
                if (pj < 56) {
                    size_t off = (size_t)(pi * 56 + pj) * CDIM + g * 8 + lic;
                    smem[rr][lic][pj + 3] = q[off] * k[off] * scale;
                }
            }
        }
    }
    __syncthreads();

    int r = r0 + waveid;
    float bias_o = b[g * 8 + oc];
    for (int j0 = 0; j0 < 56; j0 += 4) {
        float acc0 = 0.f, acc1 = 0.f, acc2 = 0.f, acc3 = 0.f;
        #pragma unroll
        for (int u = 0; u < 7; u++) {
            const float* rp = &smem[waveid + u][ic][j0];
            float4 c0 = *(const float4*)(rp);
            float4 c1 = *(const float4*)(rp + 4);
            float4 c2 = *(const float4*)(rp + 8);
            float col[12] = {c0.x, c0.y, c0.z, c0.w,
                             c1.x, c1.y, c1.z, c1.w,
                             c2.x, c2.y, c2.z, c2.w};
            #pragma unroll
            for (int v = 0; v < 7; v++) {
                float wv = wreg[u * 7 + v];
                acc0 += wv * col[v + 0];
                acc1 += wv * col[v + 1];
                acc2 += wv * col[v + 2];
                acc3 += wv * col[v + 3];
            }
        }
        float accs[4] = {acc0, acc1, acc2, acc3};
        #pragma unroll
        for (int jj = 0; jj < 4; jj++) {
            float s = accs[jj];
            s += __shfl_xor(s, 8);
            s += __shfl_xor(s, 16);
            s += __shfl_xor(s, 32);
            accs[jj] = s;
        }
        if (ic == 0) {
            #pragma unroll
            for (int jj = 0; jj < 4; jj++) {
                float a = accs[jj] + bias_o;
                float gl = 0.5f * a * (1.0f + erff(a * 0.70710678118654752f));
                int n = r * 56 + j0 + jj;
                int kch = g * 8 + oc;
                out[perm_off(n, kch, 448)] = __float2bfloat16(gl);
            }
        }
    }
}

// softmax over 392 channels, in place, one block (128 thr) per pixel
__global__ __launch_bounds__(128) void softmax392(float* __restrict__ h2)
{
    __shared__ float red[128];
    int n = blockIdx.x, tid = threadIdx.x;
    float* row = h2 + (size_t)n * C2;
    float m = -1e30f;
    for (int c = tid; c < C2; c += 128) m = fmaxf(m, row[c]);
    red[tid] = m; __syncthreads();
    for (int s = 64; s; s >>= 1) {
        if (tid < s) red[tid] = fmaxf(red[tid], red[tid + s]);
        __syncthreads();
    }
    m = red[0]; __syncthreads();
    float loc = 0.f;
    for (int c = tid; c < C2; c += 128) {
        float e = expf(row[c] - m);
        row[c] = e; loc += e;
    }
    red[tid] = loc; __syncthreads();
    for (int s = 64; s; s >>= 1) {
        if (tid < s) red[tid] += red[tid + s];
        __syncthreads();
    }
    float inv = 1.0f / red[0];
    for (int c = tid; c < C2; c += 128) row[c] *= inv;
}

// ---------------------------------------------------------------------------
// combine v3: wave per (pixel, head), lane = channel-in-head.
// Taps preloaded to lane regs, broadcast via readlane; interior fast path
// (clipped window == padded window -> single v load per tap, no bounds).
// ---------------------------------------------------------------------------
__global__ __launch_bounds__(256) void combine_v3(
    const float* __restrict__ v, const float* __restrict__ attn,
    const float* __restrict__ hat, const float* __restrict__ ghostT,
    __hip_bfloat16* __restrict__ comb)
{
    int wave = blockIdx.x * 4 + (threadIdx.x >> 6);
    wave = __builtin_amdgcn_readfirstlane(wave);
    int lane = threadIdx.x & 63;
    int n = wave >> 3, h = wave & 7;
    int i = n / 56, j = n % 56;
    int d = (lane < HD) ? lane : (HD - 1);
    int c = h * HD + d;

    float atv = 0.f, htv = 0.f;
    if (lane < KK) {
        atv = attn[(size_t)n * C2 + h * KK + lane];
        htv = hat [(size_t)n * C2 + h * KK + lane];
    }

    const float* gp = ghostT + c;
    float av = 0.f, elsa = 0.f;
    bool lo = (d < 27);

    if (i >= 3 && i <= 52 && j >= 3 && j <= 52) {
        const float* vb = v + (size_t)((i - 3) * 56 + (j - 3)) * CDIM + c;
        #pragma unroll
        for (int t = 0; t < KK; t++) {
            const int u = t / 7, vv = t % 7;
            float a_t = __shfl(atv, t);
            float h_t = __shfl(htv, t);
            float vc = vb[(u * 56 + vv) * CDIM];
            float g  = gp[t * CDIM];
            av   += (a_t + h_t) * vc;
            float asel = lo ? a_t : h_t;
            elsa += (asel + g) * vc;
        }
    } else {
        int ni = min(max(i - 3, 0), 49), nj = min(max(j - 3, 0), 49);
        const float* vb = v + (size_t)(ni * 56 + nj) * CDIM + c;
        #pragma unroll
        for (int t = 0; t < KK; t++) {
            const int u = t / 7, vv = t % 7;
            float a_t = __shfl(atv, t);
            float h_t = __shfl(htv, t);
            float vc = vb[(u * 56 + vv) * CDIM];
            av += (a_t + h_t) * vc;
            int pi = i + u - 3, pj = j + vv - 3;
            if (pi >= 0 && pi < 56 && pj >= 0 && pj < 56) {
                float vp = v[(size_t)(pi * 56 + pj) * CDIM + c];
                float g = gp[t * CDIM];
                float asel = lo ? a_t : h_t;
                elsa += (asel + g) * vp;
            }
        }
    }
    if (lane < HD) {
        comb[perm_off(n, h * 108 + d, 896)] = __float2bfloat16(av);
        comb[perm_off(n, h * 108 + 54 + d, 896)] = __float2bfloat16(elsa);
    }
}

extern "C" void kernel_launch(void* const* d_in, const int* in_sizes, int n_in,
                              void* d_out, int out_size, void* d_ws, size_t ws_size,
                              hipStream_t stream)
{
    const float* x       = (const float*)d_in[0];
    const float* qkv_w   = (const float*)d_in[1];
    const float* qkv_b   = (const float*)d_in[2];
    const float* rpb     = (const float*)d_in[3];
    const float* conv1_w = (const float*)d_in[4];
    const float* conv1_b = (const float*)d_in[5];
    const float* conv2_w = (const float*)d_in[6];
    const float* conv2_b = (const float*)d_in[7];
    const float* ghost   = (const float*)d_in[8];
    const float* proj2_w = (const float*)d_in[9];
    const float* proj2_b = (const float*)d_in[10];
    float* out = (float*)d_out;

    float* ws = (float*)d_ws;
    const size_t NC = (size_t)N_PIX * CDIM;       // 1354752
    const size_t NA = (size_t)N_PIX * C2;         // 1229312
    float* q      = ws;
    float* k      = q + NC;
    float* v      = k + NC;
    float* attn   = v + NC;
    float* hat    = attn + NA;
    float* ghostT = hat + NA;                     // 21168
    __hip_bfloat16* bfbase = (__hip_bfloat16*)(ghostT + 21168);
    __hip_bfloat16* xb     = bfbase;                    // 3136 x 448
    __hip_bfloat16* qkvwb  = xb    + (size_t)3136 * 448;
    __hip_bfloat16* c2wb   = qkvwb + (size_t)1344 * 448;
    __hip_bfloat16* p2wb   = c2wb  + (size_t)448 * 448;
    __hip_bfloat16* hb     = p2wb  + (size_t)448 * 896; // 3136 x 448
    __hip_bfloat16* cb     = hb    + (size_t)3136 * 448;// 3136 x 896

    const float scale = 0.13608276348795434f;     // 54^-0.5

    prep_kernel<<<1357, 256, 0, stream>>>(
        x, qkv_w, conv2_w, proj2_w, ghost, xb, qkvwb, c2wb, p2wb, ghostT);

    // qkv = x @ qkv_w^T + b  -> split q(*scale), k, v (fp32)
    gemm_mfma<<<dim3(21, 49), 256, 0, stream>>>(
        xb, qkvwb, qkv_b, q, k, v, 1296, 448, 0, scale, 0);

    attn_kernel<<<(N_PIX * NHEADS) / 4, 256, 0, stream>>>(q, k, rpb, attn);

    conv1_gelu_v2<<<54 * 14, 256, 0, stream>>>(q, k, conv1_w, conv1_b, hb, scale);

    gemm_mfma<<<dim3(7, 49), 256, 0, stream>>>(
        hb, c2wb, conv2_b, hat, nullptr, nullptr, 392, 448, 1, 1.f, 392);

    softmax392<<<N_PIX, 128, 0, stream>>>(hat);

    combine_v3<<<(N_PIX * NHEADS) / 4, 256, 0, stream>>>(v, attn, hat, ghostT, cb);

    gemm_mfma<<<dim3(7, 49), 256, 0, stream>>>(
        cb, p2wb, proj2_b, out, nullptr, nullptr, 432, 896, 1, 1.f, 432);
}